// Round 1
// baseline (316.728 us; speedup 1.0000x reference)
//
#include <hip/hip_runtime.h>
#include <math.h>

// Belief propagation (sum-product) on dense H [E x N].
// Key identity: output depends only on mu_c_to_v after ITERS=8 Jacobi steps,
// which equals (g.f)^4(0) -> 4 combined iterations.
// State carried: cn[c][v] = h*mu_c_to_v*w  (the only way mu enters anything).

constexpr int N = 4096;            // variable nodes
constexpr int E = 2048;            // check nodes
constexpr int COMBINED = 4;        // = ITERS/2 (ITERS=8 fixed by problem)
constexpr int CHUNK = 16;          // columns per thread in check kernel
constexpr int BT = N / CHUNK;      // 256 threads per check block
constexpr int ROWS_PER_CS = 64;    // rows per colsum block
constexpr int CS_Y = E / ROWS_PER_CS; // 32 partials

// ---- pack h (int32 0/1) into bitmask: 1 bit per entry, wave ballot ----
__global__ void pack_h_kernel(const int* __restrict__ h, unsigned int* __restrict__ hbits) {
    int idx = blockIdx.x * blockDim.x + threadIdx.x;      // one h element per thread
    int bit = (h[idx] != 0) ? 1 : 0;
    unsigned long long mask = __ballot(bit);              // 64-bit on CDNA
    if ((threadIdx.x & 63) == 0) {                        // lane 0: idx is wave base (mult of 64)
        int wb = idx >> 5;                                // even
        hbits[wb]     = (unsigned int)(mask & 0xFFFFFFFFull);
        hbits[wb + 1] = (unsigned int)(mask >> 32);
    }
}

__global__ void init_total_kernel(const float* __restrict__ l_v, const float* __restrict__ b,
                                  float* __restrict__ total) {
    int v = blockIdx.x * blockDim.x + threadIdx.x;
    total[v] = l_v[v] * b[v];                             // base
}

// ---- column sums of cn -> partial[CS_Y][N] (no atomics, deterministic) ----
__global__ void colsum_partial_kernel(const float* __restrict__ cn, float* __restrict__ partial) {
    int col = blockIdx.x * blockDim.x + threadIdx.x;
    const float* p = cn + (size_t)blockIdx.y * ROWS_PER_CS * N + col;
    float s = 0.f;
    #pragma unroll
    for (int r = 0; r < ROWS_PER_CS; ++r) s += p[(size_t)r * N];
    partial[blockIdx.y * N + col] = s;
}

__global__ void reduce_total_kernel(const float* __restrict__ partial,
                                    const float* __restrict__ l_v, const float* __restrict__ b,
                                    float* __restrict__ total) {
    int v = blockIdx.x * blockDim.x + threadIdx.x;
    float s = l_v[v] * b[v];
    #pragma unroll
    for (int j = 0; j < CS_Y; ++j) s += partial[j * N + v];
    total[v] = s;
}

// ---- combined check update: one block per check row c ----
// m[v] = total[v] - cn[c][v]; T = h ? tanh(m/2) : 1; excl = row-exclusive-product(T);
// cn_new[c][v] = h ? w * sign*2*atanh(excl) : 0
template <bool FIRST>
__global__ __launch_bounds__(BT) void check_update_kernel(
    const unsigned int* __restrict__ hbits, const float* __restrict__ w,
    const int* __restrict__ s_c, const float* __restrict__ total,
    float* __restrict__ cn) {
    const int c = blockIdx.x;
    const int t = threadIdx.x;
    const int col0 = t * CHUNK;
    const size_t rowOff = (size_t)c * N;

    unsigned int word = hbits[c * (N / 32) + (t >> 1)];
    unsigned int bits = (word >> ((t & 1) * 16)) & 0xFFFFu;

    // load total (and cn) for my 16 contiguous columns
    float m[CHUNK];
    {
        const float4* t4 = reinterpret_cast<const float4*>(total + col0);
        float4 a0 = t4[0], a1 = t4[1], a2 = t4[2], a3 = t4[3];
        float tot[CHUNK] = {a0.x,a0.y,a0.z,a0.w, a1.x,a1.y,a1.z,a1.w,
                            a2.x,a2.y,a2.z,a2.w, a3.x,a3.y,a3.z,a3.w};
        if (FIRST) {
            #pragma unroll
            for (int j = 0; j < CHUNK; ++j) m[j] = tot[j];
        } else {
            const float4* c4 = reinterpret_cast<const float4*>(cn + rowOff + col0);
            float4 b0 = c4[0], b1 = c4[1], b2 = c4[2], b3 = c4[3];
            float cv[CHUNK] = {b0.x,b0.y,b0.z,b0.w, b1.x,b1.y,b1.z,b1.w,
                               b2.x,b2.y,b2.z,b2.w, b3.x,b3.y,b3.z,b3.w};
            #pragma unroll
            for (int j = 0; j < CHUNK; ++j) m[j] = tot[j] - cv[j];
        }
    }

    float T[CHUNK];
    float p = 1.f;
    #pragma unroll
    for (int j = 0; j < CHUNK; ++j) {
        float th = tanhf(0.5f * m[j]);
        T[j] = ((bits >> j) & 1u) ? th : 1.0f;
        p *= T[j];
    }

    // block-wide prefix and suffix product scans (division-free: zeros ok)
    __shared__ float sf[BT], sb[BT];
    sf[t] = p;
    sb[BT - 1 - t] = p;
    __syncthreads();
    #pragma unroll
    for (int s = 1; s < BT; s <<= 1) {
        float vf = (t >= s) ? sf[t - s] : 1.f;
        float vb = (t >= s) ? sb[t - s] : 1.f;
        __syncthreads();
        sf[t] *= vf;
        sb[t] *= vb;
        __syncthreads();
    }
    float pre = (t > 0) ? sf[t - 1] : 1.f;            // prod of chunks before mine
    float suf = (t < BT - 1) ? sb[BT - 2 - t] : 1.f;  // prod of chunks after mine

    // within-chunk exclusive product
    float e[CHUNK];
    float run = suf;
    #pragma unroll
    for (int j = CHUNK - 1; j >= 0; --j) { e[j] = run; run *= T[j]; }

    const float sgn2 = (s_c[c] != 0) ? -2.f : 2.f;
    const float4* w4 = reinterpret_cast<const float4*>(w + rowOff + col0);
    float4 w0 = w4[0], w1 = w4[1], w2 = w4[2], w3 = w4[3];
    float wv[CHUNK] = {w0.x,w0.y,w0.z,w0.w, w1.x,w1.y,w1.z,w1.w,
                       w2.x,w2.y,w2.z,w2.w, w3.x,w3.y,w3.z,w3.w};

    float o[CHUNK];
    float run2 = pre;
    #pragma unroll
    for (int j = 0; j < CHUNK; ++j) {
        float excl = run2 * e[j];
        run2 *= T[j];
        float val = sgn2 * atanhf(excl) * wv[j];
        o[j] = ((bits >> j) & 1u) ? val : 0.f;
    }
    float4* o4 = reinterpret_cast<float4*>(cn + rowOff + col0);
    o4[0] = make_float4(o[0], o[1], o[2], o[3]);
    o4[1] = make_float4(o[4], o[5], o[6], o[7]);
    o4[2] = make_float4(o[8], o[9], o[10], o[11]);
    o4[3] = make_float4(o[12], o[13], o[14], o[15]);
}

__global__ void out_kernel(const float* __restrict__ total, float* __restrict__ outp) {
    int v = blockIdx.x * blockDim.x + threadIdx.x;
    outp[v] = 1.0f / (expf(total[v]) + 1.0f);   // hf_sigmoid
}

extern "C" void kernel_launch(void* const* d_in, const int* in_sizes, int n_in,
                              void* d_out, int out_size, void* d_ws, size_t ws_size,
                              hipStream_t stream) {
    const float* l_v = (const float*)d_in[0];
    const int*   h   = (const int*)d_in[1];
    const int*   s_c = (const int*)d_in[2];
    // d_in[3] = iterations (fixed at 8 by the problem; combined = 4)
    const float* b   = (const float*)d_in[4];
    const float* w   = (const float*)d_in[5];
    float* out = (float*)d_out;

    char* ws = (char*)d_ws;
    float* cn           = (float*)(ws);                                  // 32 MB
    float* partial      = (float*)(ws + (size_t)E * N * 4);              // 512 KB
    float* total        = (float*)(ws + (size_t)E * N * 4 + (size_t)CS_Y * N * 4); // 16 KB
    unsigned int* hbits = (unsigned int*)(ws + (size_t)E * N * 4 + (size_t)CS_Y * N * 4 + (size_t)N * 4); // 1 MB

    pack_h_kernel<<<(E * N) / 256, 256, 0, stream>>>(h, hbits);
    init_total_kernel<<<N / 256, 256, 0, stream>>>(l_v, b, total);
    check_update_kernel<true><<<E, BT, 0, stream>>>(hbits, w, s_c, total, cn);
    for (int k = 1; k < COMBINED; ++k) {
        colsum_partial_kernel<<<dim3(N / 256, CS_Y), 256, 0, stream>>>(cn, partial);
        reduce_total_kernel<<<N / 256, 256, 0, stream>>>(partial, l_v, b, total);
        check_update_kernel<false><<<E, BT, 0, stream>>>(hbits, w, s_c, total, cn);
    }
    colsum_partial_kernel<<<dim3(N / 256, CS_Y), 256, 0, stream>>>(cn, partial);
    reduce_total_kernel<<<N / 256, 256, 0, stream>>>(partial, l_v, b, total);
    out_kernel<<<N / 256, 256, 0, stream>>>(total, out);
}

// Round 2
// 223.362 us; speedup vs baseline: 1.4180x; 1.4180x over previous
//
#include <hip/hip_runtime.h>
#include <math.h>

// Belief propagation (sum-product) on dense H [E x N].
// Identity: output depends only on mu_c_to_v after ITERS=8 Jacobi steps,
// which equals (g.f)^4(0) -> 4 combined iterations.
// State: cn[c][v] = h*mu_c_to_v*w  (the only way mu enters anything).
// Exclusive row product via (product-of-nonzeros, zero-count): division only
// when no zeros in row; underflow-to-0 matches reference cumprod semantics.

constexpr int N = 4096;            // variable nodes
constexpr int E = 2048;            // check nodes
constexpr int COMBINED = 4;        // = ITERS/2 (ITERS=8 fixed by problem)
constexpr int CHUNK = 16;          // columns per thread in check kernel
constexpr int BT = N / CHUNK;      // 256 threads per check block
constexpr int NWAVES = BT / 64;    // 4
constexpr int ROWS_PER_CS = 32;    // rows per colsum block
constexpr int CS_Y = E / ROWS_PER_CS; // 64 partials

// ---- pack h (int32 0/1) into bitmask ----
__global__ void pack_h_kernel(const int* __restrict__ h, unsigned int* __restrict__ hbits) {
    int idx = blockIdx.x * blockDim.x + threadIdx.x;
    int bit = (h[idx] != 0) ? 1 : 0;
    unsigned long long mask = __ballot(bit);
    if ((threadIdx.x & 63) == 0) {
        int wb = idx >> 5;
        hbits[wb]     = (unsigned int)(mask & 0xFFFFFFFFull);
        hbits[wb + 1] = (unsigned int)(mask >> 32);
    }
}

// ---- column sums of cn -> partial[CS_Y][N], float4 ----
__global__ void colsum_partial_kernel(const float* __restrict__ cn, float* __restrict__ partial) {
    int c4 = blockIdx.x * blockDim.x + threadIdx.x;      // float4 col index
    const float4* p = reinterpret_cast<const float4*>(cn)
                      + (size_t)blockIdx.y * ROWS_PER_CS * (N / 4) + c4;
    float4 s = make_float4(0.f, 0.f, 0.f, 0.f);
    #pragma unroll
    for (int r = 0; r < ROWS_PER_CS; ++r) {
        float4 v = p[(size_t)r * (N / 4)];
        s.x += v.x; s.y += v.y; s.z += v.z; s.w += v.w;
    }
    reinterpret_cast<float4*>(partial)[(size_t)blockIdx.y * (N / 4) + c4] = s;
}

template <bool FINAL>
__global__ void reduce_total_kernel(const float* __restrict__ partial,
                                    const float* __restrict__ l_v, const float* __restrict__ b,
                                    float* __restrict__ dst) {
    int v = blockIdx.x * blockDim.x + threadIdx.x;
    float s = l_v[v] * b[v];
    #pragma unroll
    for (int j = 0; j < CS_Y; ++j) s += partial[j * N + v];
    dst[v] = FINAL ? 1.0f / (__expf(s) + 1.0f) : s;    // hf_sigmoid at the end
}

// ---- combined check update: one block per check row c ----
// m = total - cn_row; T = h ? tanh(m/2) : 1; excl = exclusive row product;
// cn_new = h ? w * sign * 2*atanh(excl) : 0
template <bool FIRST>
__global__ __launch_bounds__(BT) void check_update_kernel(
    const unsigned int* __restrict__ hbits, const float* __restrict__ w,
    const int* __restrict__ s_c, const float* __restrict__ total,
    const float* __restrict__ l_v, const float* __restrict__ bv,
    float* __restrict__ cn) {
    const int c = blockIdx.x;
    const int t = threadIdx.x;
    const int col0 = t * CHUNK;
    const size_t rowOff = (size_t)c * N;

    unsigned int word = hbits[c * (N / 32) + (t >> 1)];
    unsigned int bits = (word >> ((t & 1) * 16)) & 0xFFFFu;

    // m for my 16 contiguous columns
    float m[CHUNK];
    if (FIRST) {
        const float4* lv4 = reinterpret_cast<const float4*>(l_v + col0);
        const float4* bb4 = reinterpret_cast<const float4*>(bv + col0);
        #pragma unroll
        for (int q = 0; q < 4; ++q) {
            float4 a = lv4[q], d = bb4[q];
            m[4*q+0] = a.x * d.x; m[4*q+1] = a.y * d.y;
            m[4*q+2] = a.z * d.z; m[4*q+3] = a.w * d.w;
        }
    } else {
        const float4* t4 = reinterpret_cast<const float4*>(total + col0);
        const float4* c4 = reinterpret_cast<const float4*>(cn + rowOff + col0);
        #pragma unroll
        for (int q = 0; q < 4; ++q) {
            float4 a = t4[q], d = c4[q];
            m[4*q+0] = a.x - d.x; m[4*q+1] = a.y - d.y;
            m[4*q+2] = a.z - d.z; m[4*q+3] = a.w - d.w;
        }
    }

    // T = tanh(m/2) = (e^m - 1)/(e^m + 1), fast pipes; clamp avoids inf*0 NaN
    float T[CHUNK];
    float p = 1.f;
    int zc = 0;
    #pragma unroll
    for (int j = 0; j < CHUNK; ++j) {
        float mc = fminf(fmaxf(m[j], -30.f), 30.f);
        float em = __expf(mc);
        float th = (em - 1.f) * __builtin_amdgcn_rcpf(em + 1.f);
        float Tj = ((bits >> j) & 1u) ? th : 1.0f;
        T[j] = Tj;
        if (Tj == 0.f) zc++; else p *= Tj;
    }

    // wave butterfly reduce (product of nonzeros, zero count)
    #pragma unroll
    for (int s = 1; s < 64; s <<= 1) {
        p  *= __shfl_xor(p, s, 64);
        zc += __shfl_xor(zc, s, 64);
    }
    // cross-wave combine (4 waves)
    __shared__ float pw[NWAVES];
    __shared__ int   zw[NWAVES];
    const int wid = t >> 6;
    if ((t & 63) == 0) { pw[wid] = p; zw[wid] = zc; }
    __syncthreads();
    float P = 1.f;
    int  ZC = 0;
    #pragma unroll
    for (int u = 0; u < NWAVES; ++u) { P *= pw[u]; ZC += zw[u]; }

    const float sgn = (s_c[c] != 0) ? -1.f : 1.f;
    const float4* w4 = reinterpret_cast<const float4*>(w + rowOff + col0);
    float4 w0 = w4[0], w1 = w4[1], w2 = w4[2], w3 = w4[3];
    float wv[CHUNK] = {w0.x,w0.y,w0.z,w0.w, w1.x,w1.y,w1.z,w1.w,
                       w2.x,w2.y,w2.z,w2.w, w3.x,w3.y,w3.z,w3.w};

    float o[CHUNK];
    #pragma unroll
    for (int j = 0; j < CHUNK; ++j) {
        float excl;
        if (ZC == 0)      excl = __fdividef(P, T[j]);        // all T nonzero
        else if (ZC == 1) excl = (T[j] == 0.f) ? P : 0.f;
        else              excl = 0.f;
        // sign*2*atanh(excl) = sign*ln((1+excl)/(1-excl)); log(1)=0 exactly
        float val = sgn * __logf(__fdividef(1.f + excl, 1.f - excl)) * wv[j];
        o[j] = ((bits >> j) & 1u) ? val : 0.f;
    }
    float4* o4 = reinterpret_cast<float4*>(cn + rowOff + col0);
    o4[0] = make_float4(o[0],  o[1],  o[2],  o[3]);
    o4[1] = make_float4(o[4],  o[5],  o[6],  o[7]);
    o4[2] = make_float4(o[8],  o[9],  o[10], o[11]);
    o4[3] = make_float4(o[12], o[13], o[14], o[15]);
}

extern "C" void kernel_launch(void* const* d_in, const int* in_sizes, int n_in,
                              void* d_out, int out_size, void* d_ws, size_t ws_size,
                              hipStream_t stream) {
    const float* l_v = (const float*)d_in[0];
    const int*   h   = (const int*)d_in[1];
    const int*   s_c = (const int*)d_in[2];
    // d_in[3] = iterations (8 fixed; combined = 4)
    const float* b   = (const float*)d_in[4];
    const float* w   = (const float*)d_in[5];
    float* out = (float*)d_out;

    char* ws = (char*)d_ws;
    float* cn           = (float*)(ws);                                   // 32 MB
    float* partial      = (float*)(ws + (size_t)E * N * 4);               // 1 MB
    float* total        = (float*)(ws + (size_t)E * N * 4 + (size_t)CS_Y * N * 4);
    unsigned int* hbits = (unsigned int*)(ws + (size_t)E * N * 4
                                          + (size_t)CS_Y * N * 4 + (size_t)N * 4);

    pack_h_kernel<<<(E * N) / 256, 256, 0, stream>>>(h, hbits);
    check_update_kernel<true><<<E, BT, 0, stream>>>(hbits, w, s_c, total, l_v, b, cn);
    for (int k = 1; k < COMBINED; ++k) {
        colsum_partial_kernel<<<dim3(N / 4 / 256, CS_Y), 256, 0, stream>>>(cn, partial);
        reduce_total_kernel<false><<<N / 256, 256, 0, stream>>>(partial, l_v, b, total);
        check_update_kernel<false><<<E, BT, 0, stream>>>(hbits, w, s_c, total, l_v, b, cn);
    }
    colsum_partial_kernel<<<dim3(N / 4 / 256, CS_Y), 256, 0, stream>>>(cn, partial);
    reduce_total_kernel<true><<<N / 256, 256, 0, stream>>>(partial, l_v, b, out);
}